// Round 16
// baseline (744.476 us; speedup 1.0000x reference)
//
#include <hip/hip_runtime.h>
#include <stdint.h>

#define Bsz  512
#define Tlen 50
#define Hdim 128
#define GB   2            // batch elements per block
#define NBLK (Bsz/GB)     // 256 blocks -> 1 per CU
#define NTHR 1024         // 16 waves
#define BIG  100000000.0f
#define TINYF 1.17549435e-38f

struct U2 { uint32_t a, b; };

// Exact JAX threefry2x32 (5 groups of 4 rounds).
__device__ __forceinline__ U2 tf2x32(uint32_t k0, uint32_t k1, uint32_t x0, uint32_t x1) {
  uint32_t k2 = k0 ^ k1 ^ 0x1BD11BDAu;
  x0 += k0; x1 += k1;
#define RR(r) { x0 += x1; x1 = (x1 << (r)) | (x1 >> (32 - (r))); x1 ^= x0; }
  RR(13) RR(15) RR(26) RR(6)
  x0 += k1; x1 += k2 + 1u;
  RR(17) RR(29) RR(16) RR(24)
  x0 += k2; x1 += k0 + 2u;
  RR(13) RR(15) RR(26) RR(6)
  x0 += k0; x1 += k1 + 3u;
  RR(17) RR(29) RR(16) RR(24)
  x0 += k1; x1 += k2 + 4u;
  RR(13) RR(15) RR(26) RR(6)
  x0 += k2; x1 += k0 + 5u;
#undef RR
  U2 r; r.a = x0; r.b = x1; return r;
}

// fast tanh for attention scores (numerics preserved from passing kernels)
__device__ __forceinline__ float fast_tanh(float x) {
  float xc = fminf(fmaxf(x, -9.0f), 9.0f);
  float e = __expf(2.0f * xc);
  return (e - 1.0f) / (e + 1.0f);
}

// -------- prep: transpose + float4-pack weights into workspace --------
// WTP  : [64][512][4]  combined gate weights; kb<32 -> W_ih k=kb*4+j ; kb>=32 -> W_hh
// WoT4 : [32][128][4]  W_out^T packed
// WrT4 : [32][128][4]  W_ref^T packed
__global__ void prep_kernel(const float* __restrict__ W_ih, const float* __restrict__ W_hh,
                            const float* __restrict__ W_out, const float* __restrict__ W_ref,
                            float* __restrict__ WTP, float* __restrict__ WoT4,
                            float* __restrict__ WrT4) {
  int idx = blockIdx.x * blockDim.x + threadIdx.x;
  if (idx < 131072) {
    int j  = idx & 3;
    int r  = (idx >> 2) & 511;
    int kb = idx >> 11;
    int k  = kb * 4 + j;
    WTP[idx] = (k < Hdim) ? W_ih[r * Hdim + k] : W_hh[r * Hdim + (k - Hdim)];
  } else if (idx < 131072 + 16384) {
    int i2 = idx - 131072;
    int j = i2 & 3, o = (i2 >> 2) & 127, kb = i2 >> 9;
    WoT4[i2] = W_out[o * Hdim + (kb * 4 + j)];
  } else if (idx < 131072 + 32768) {
    int i3 = idx - 147456;
    int j = i3 & 3, o = (i3 >> 2) & 127, hb = i3 >> 9;
    WrT4[i3] = W_ref[o * Hdim + (hb * 4 + j)];
  }
}

// ------------------------------ main ------------------------------
// R13 champion (626 us) with unroll 8 on the three per-step streaming GEMV
// loops (ah halves, A phase) to double outstanding global loads. VGPR budget
// is licensed by __launch_bounds__(1024,4) (cap 128); R7's unroll-8 spill was
// under the old 64-VGPR cap. All fmaf chains bit-identical (pragmas only).
// Per-step schedule (5 barriers):
//   B: gates combine + LSTM (256 thr)
//   C: dec_term (256 thr, LDS W_out)  ||  waves 8-15: ah_{t+1} kb 0..15 (regs)
//   D: scores (waves 0-7)             ||  waves 8-15: ah_{t+1} kb 16..31 -> s_ah
//   E: sample (waves 0-1, LDS gumbel table) -> s_loc
//   A: ax_{t+1} = wx . enc[bg, loc]   (waves 0-7)
__global__ __launch_bounds__(NTHR, 4) void actor_main(
    const float* __restrict__ enc, const float* __restrict__ h0,
    const float* __restrict__ c0, const float* __restrict__ b_ih,
    const float* __restrict__ b_hh, const float* __restrict__ go,
    const float* __restrict__ v, const float* __restrict__ WTP,
    const float* __restrict__ WoT4, const float* __restrict__ WrT4,
    float* __restrict__ out)
{
  __shared__ __align__(16) float s_encterm[GB][Tlen][Hdim]; // 50 KB
  __shared__ __align__(16) float s_xh[GB][2 * Hdim];        // x | h (x used only at t=0)
  __shared__ __align__(16) float s_c[GB][Hdim];
  __shared__ __align__(16) float s_ax[GB][4 * Hdim];        // x-partials
  __shared__ __align__(16) float s_ah[GB][4 * Hdim];        // h-partials
  __shared__ __align__(16) float s_dec[GB][Hdim];
  __shared__ __align__(16) float4 s_wout4[32 * 128];        // 64 KB W_out^T
  __shared__ float s_gum[Tlen][GB][Tlen];                   // 20 KB precomputed gumbel
  __shared__ float s_scores[GB][Tlen];
  __shared__ float s_mask[GB][Tlen];
  __shared__ __align__(16) float s_bih[4 * Hdim];
  __shared__ __align__(16) float s_bhh[4 * Hdim];
  __shared__ __align__(16) float s_v[Hdim];
  __shared__ float s_logp[GB];
  __shared__ int   s_loc[GB];

  const int tid = threadIdx.x;
  const int b0  = blockIdx.x * GB;

  // ---- init ----
  for (int i = tid; i < 4 * Hdim; i += NTHR) { s_bih[i] = b_ih[i]; s_bhh[i] = b_hh[i]; }
  for (int i = tid; i < Hdim; i += NTHR) s_v[i] = v[i];
  for (int i = tid; i < GB * Hdim; i += NTHR) {
    int b = i >> 7, jj = i & 127;
    s_xh[b][jj]        = go[jj];
    s_xh[b][Hdim + jj] = h0[(size_t)(b0 + b) * Hdim + jj];
    s_c[b][jj]         = c0[(size_t)(b0 + b) * Hdim + jj];
  }
  for (int i = tid; i < GB * Tlen; i += NTHR) (&s_mask[0][0])[i] = 0.0f;
  if (tid < GB) s_logp[tid] = 0.0f;
  {
    const float4* src = (const float4*)WoT4;
    for (int i = tid; i < 32 * 128; i += NTHR) s_wout4[i] = src[i];
  }
  // gumbel table: identical op chain as the per-step E computation
  for (int i = tid; i < Tlen * GB * Tlen; i += NTHR) {
    int t    = i / (GB * Tlen);
    int rem  = i - t * (GB * Tlen);
    int b    = rem / Tlen;
    int lane = rem - b * Tlen;
    int bg   = b0 + b;
    U2 sk = tf2x32(0u, 42u, 0u, (uint32_t)t);
    U2 rb = tf2x32(sk.a, sk.b, 0u, (uint32_t)(bg * Tlen + lane));
    uint32_t bits = rb.a ^ rb.b;
    float f = __uint_as_float((bits >> 9) | 0x3f800000u) - 1.0f;
    float u = fmaxf(f, TINYF);
    s_gum[t][b][lane] = -logf(-logf(u));
  }

  // ---- enc_term = einsum('bth,oh->bto', enc, W_ref), per-block slice ----
  {
    const float4* Wr4 = (const float4*)WrT4;
    for (int oidx = tid; oidx < GB * Tlen * Hdim; oidx += NTHR) {
      int b = oidx / (Tlen * Hdim);
      int rem = oidx - b * (Tlen * Hdim);
      int t = rem >> 7, o = rem & 127;
      const float4* ep4 = (const float4*)(enc + ((size_t)(b0 + b) * Tlen + t) * Hdim);
      float acc = 0.0f;
#pragma unroll 4
      for (int hb = 0; hb < 32; ++hb) {
        float4 e4 = ep4[hb];
        float4 w4 = Wr4[hb * 128 + o];
        acc = fmaf(e4.x, w4.x, acc); acc = fmaf(e4.y, w4.y, acc);
        acc = fmaf(e4.z, w4.z, acc); acc = fmaf(e4.w, w4.w, acc);
      }
      s_encterm[b][t][o] = acc;
    }
  }
  __syncthreads();

  const float4* W4 = (const float4*)WTP;

  // ---- A0: ax_0 (x=go, waves 0-7) and ah_0 (waves 8-15) — verbatim R8 ----
  {
    int r    = tid & 511;
    int part = tid >> 9;            // 0 = x-part, 1 = h-part
    int xoff = part * Hdim;
    int woff = part * 32;
    const float4* vA = (const float4*)&s_xh[0][xoff];
    const float4* vB = (const float4*)&s_xh[1][xoff];
    float a0 = 0.f, a1 = 0.f;
#pragma unroll 4
    for (int kb = 0; kb < 32; ++kb) {
      float4 w4 = W4[(kb + woff) * 512 + r];
      float4 f0 = vA[kb];
      float4 f1 = vB[kb];
      a0 = fmaf(f0.x, w4.x, a0); a0 = fmaf(f0.y, w4.y, a0);
      a0 = fmaf(f0.z, w4.z, a0); a0 = fmaf(f0.w, w4.w, a0);
      a1 = fmaf(f1.x, w4.x, a1); a1 = fmaf(f1.y, w4.y, a1);
      a1 = fmaf(f1.z, w4.z, a1); a1 = fmaf(f1.w, w4.w, a1);
    }
    if (part == 0) { s_ax[0][r] = a0; s_ax[1][r] = a1; }
    else           { s_ah[0][r] = a0; s_ah[1][r] = a1; }
  }
  __syncthreads();

  for (int t = 0; t < Tlen; ++t) {
    const bool not_last = (t < Tlen - 1);
    float ahA = 0.f, ahB = 0.f;          // ah_{t+1} accumulators (waves 8-15)
    const int r = tid & 511;

    // ---- B: gates = ((ax + bih) + ah) + bhh ; LSTM pointwise ----
    if (tid < GB * Hdim) {
      int b = tid >> 7, jj = tid & 127;
      float gi  = ((s_ax[b][jj]          + s_bih[jj])          + s_ah[b][jj])          + s_bhh[jj];
      float gf  = ((s_ax[b][Hdim + jj]   + s_bih[Hdim + jj])   + s_ah[b][Hdim + jj])   + s_bhh[Hdim + jj];
      float gg  = ((s_ax[b][2*Hdim + jj] + s_bih[2*Hdim + jj]) + s_ah[b][2*Hdim + jj]) + s_bhh[2*Hdim + jj];
      float gob = ((s_ax[b][3*Hdim + jj] + s_bih[3*Hdim + jj]) + s_ah[b][3*Hdim + jj]) + s_bhh[3*Hdim + jj];
      float i_ = 1.0f / (1.0f + expf(-gi));
      float f_ = 1.0f / (1.0f + expf(-gf));
      float g_ = tanhf(gg);
      float o_ = 1.0f / (1.0f + expf(-gob));
      float cn = f_ * s_c[b][jj] + i_ * g_;
      s_c[b][jj] = cn;
      s_xh[b][Hdim + jj] = o_ * tanhf(cn);
    }
    __syncthreads();

    // ---- C: dec_term (256 thr, LDS W_out)  ||  waves 8-15: ah kb 0..15 ----
    if (tid < GB * Hdim) {
      int b = tid >> 7, o = tid & 127;
      float acc = 0.0f;
#pragma unroll 4
      for (int kb = 0; kb < 32; ++kb) {
        float4 w4 = s_wout4[kb * 128 + o];
        float4 h4 = *(const float4*)&s_xh[b][Hdim + kb * 4];
        acc = fmaf(h4.x, w4.x, acc); acc = fmaf(h4.y, w4.y, acc);
        acc = fmaf(h4.z, w4.z, acc); acc = fmaf(h4.w, w4.w, acc);
      }
      s_dec[b][o] = acc;
    } else if (tid >= 512 && not_last) {
      const float4* vA = (const float4*)&s_xh[0][Hdim];
      const float4* vB = (const float4*)&s_xh[1][Hdim];
#pragma unroll 8
      for (int kb = 0; kb < 16; ++kb) {
        float4 w4 = W4[(kb + 32) * 512 + r];
        float4 f0 = vA[kb];
        float4 f1 = vB[kb];
        ahA = fmaf(f0.x, w4.x, ahA); ahA = fmaf(f0.y, w4.y, ahA);
        ahA = fmaf(f0.z, w4.z, ahA); ahA = fmaf(f0.w, w4.w, ahA);
        ahB = fmaf(f1.x, w4.x, ahB); ahB = fmaf(f1.y, w4.y, ahB);
        ahB = fmaf(f1.z, w4.z, ahB); ahB = fmaf(f1.w, w4.w, ahB);
      }
    }
    __syncthreads();

    // ---- D: scores (waves 0-7)  ||  waves 8-15: ah kb 16..31 -> s_ah ----
    if (tid < 512) {
      int w = tid >> 6, lane = tid & 63;
      float vlo = s_v[lane], vhi = s_v[lane + 64];
      for (int task = w; task < GB * Tlen; task += 8) {
        int b = task / Tlen, tt = task - b * Tlen;
        float p0 = s_encterm[b][tt][lane]      + s_dec[b][lane];
        float p1 = s_encterm[b][tt][lane + 64] + s_dec[b][lane + 64];
        float val = vlo * fast_tanh(p0) + vhi * fast_tanh(p1);
        for (int off = 32; off; off >>= 1) val += __shfl_down(val, off);
        if (lane == 0) s_scores[b][tt] = val;
      }
    } else if (not_last) {
      const float4* vA = (const float4*)&s_xh[0][Hdim];
      const float4* vB = (const float4*)&s_xh[1][Hdim];
#pragma unroll 8
      for (int kb = 16; kb < 32; ++kb) {
        float4 w4 = W4[(kb + 32) * 512 + r];
        float4 f0 = vA[kb];
        float4 f1 = vB[kb];
        ahA = fmaf(f0.x, w4.x, ahA); ahA = fmaf(f0.y, w4.y, ahA);
        ahA = fmaf(f0.z, w4.z, ahA); ahA = fmaf(f0.w, w4.w, ahA);
        ahB = fmaf(f1.x, w4.x, ahB); ahB = fmaf(f1.y, w4.y, ahB);
        ahB = fmaf(f1.z, w4.z, ahB); ahB = fmaf(f1.w, w4.w, ahB);
      }
      s_ah[0][r] = ahA; s_ah[1][r] = ahB;
    }
    __syncthreads();

    // ---- E: sample (waves 0-1, LDS gumbel) -> tour, logp, mask, s_loc ----
    {
      int w = tid >> 6;
      if (w < GB) {
        int b = w, lane = tid & 63;
        int bg = b0 + b;
        float masked_v = -3.0e38f, val = -3.0e38f;
        if (lane < Tlen) {
          float sc = s_scores[b][lane];
          float mk = s_mask[b][lane];
          masked_v = sc - BIG * mk;
          val = masked_v + s_gum[t][b][lane];
        }
        // argmax, first-index tie-break
        float bv = val; int bi = (tid & 63);
        for (int off = 32; off; off >>= 1) {
          float ov = __shfl_down(bv, off);
          int   oi = __shfl_down(bi, off);
          if (ov > bv || (ov == bv && oi < bi)) { bv = ov; bi = oi; }
        }
        bi = __shfl(bi, 0);
        // log_softmax at bi
        float mx = masked_v;
        for (int off = 32; off; off >>= 1) mx = fmaxf(mx, __shfl_down(mx, off));
        mx = __shfl(mx, 0);
        float ex = (lane < Tlen) ? expf(masked_v - mx) : 0.0f;
        for (int off = 32; off; off >>= 1) ex += __shfl_down(ex, off);
        ex = __shfl(ex, 0);
        float msel = __shfl(masked_v, bi);
        float logp = (msel - mx) - logf(ex);
        if (lane == 0) {
          s_logp[b] += logp;
          s_mask[b][bi] += 1.0f;
          s_loc[b] = bi;
          out[Bsz + (size_t)bg * (Tlen + 1) + t] = (float)bi;
          if (t == 0) out[Bsz + (size_t)bg * (Tlen + 1) + Tlen] = (float)bi;
        }
      }
    }
    __syncthreads();

    // ---- A: ax_{t+1} = wx . enc[bg, loc]  (waves 0-7, direct L2 row reads) ----
    if (tid < 512 && not_last) {
      const float4* eA = (const float4*)(enc + ((size_t)(b0 + 0) * Tlen + s_loc[0]) * Hdim);
      const float4* eB = (const float4*)(enc + ((size_t)(b0 + 1) * Tlen + s_loc[1]) * Hdim);
      float a0 = 0.f, a1 = 0.f;
#pragma unroll 8
      for (int kb = 0; kb < 32; ++kb) {
        float4 w4 = W4[kb * 512 + r];
        float4 f0 = eA[kb];
        float4 f1 = eB[kb];
        a0 = fmaf(f0.x, w4.x, a0); a0 = fmaf(f0.y, w4.y, a0);
        a0 = fmaf(f0.z, w4.z, a0); a0 = fmaf(f0.w, w4.w, a0);
        a1 = fmaf(f1.x, w4.x, a1); a1 = fmaf(f1.y, w4.y, a1);
        a1 = fmaf(f1.z, w4.z, a1); a1 = fmaf(f1.w, w4.w, a1);
      }
      s_ax[0][r] = a0; s_ax[1][r] = a1;
    }
    __syncthreads();
  }

  if (tid < GB) out[b0 + tid] = s_logp[tid];
}

extern "C" void kernel_launch(void* const* d_in, const int* in_sizes, int n_in,
                              void* d_out, int out_size, void* d_ws, size_t ws_size,
                              hipStream_t stream) {
  const float* enc   = (const float*)d_in[0];
  const float* h0    = (const float*)d_in[1];
  const float* c0    = (const float*)d_in[2];
  const float* W_ih  = (const float*)d_in[3];
  const float* W_hh  = (const float*)d_in[4];
  const float* b_ih  = (const float*)d_in[5];
  const float* b_hh  = (const float*)d_in[6];
  const float* go    = (const float*)d_in[7];
  const float* W_ref = (const float*)d_in[8];
  const float* W_out = (const float*)d_in[9];
  const float* v     = (const float*)d_in[10];
  float* out = (float*)d_out;

  float* WTP  = (float*)d_ws;        // 131072 floats (512 KB)
  float* WoT4 = WTP + 131072;        // 16384 floats
  float* WrT4 = WoT4 + 16384;        // 16384 floats  (total 640 KB of ws)

  prep_kernel<<<640, 256, 0, stream>>>(W_ih, W_hh, W_out, W_ref, WTP, WoT4, WrT4);
  actor_main<<<NBLK, NTHR, 0, stream>>>(enc, h0, c0, b_ih, b_hh, go, v,
                                        WTP, WoT4, WrT4, out);
}

// Round 18
// 626.470 us; speedup vs baseline: 1.1884x; 1.1884x over previous
//
#include <hip/hip_runtime.h>
#include <stdint.h>

#define Bsz  512
#define Tlen 50
#define Hdim 128
#define GB   2            // batch elements per block
#define NBLK (Bsz/GB)     // 256 blocks -> 1 per CU
#define NTHR 1024         // 16 waves
#define BIG  100000000.0f
#define TINYF 1.17549435e-38f

struct U2 { uint32_t a, b; };

// Exact JAX threefry2x32 (5 groups of 4 rounds).
__device__ __forceinline__ U2 tf2x32(uint32_t k0, uint32_t k1, uint32_t x0, uint32_t x1) {
  uint32_t k2 = k0 ^ k1 ^ 0x1BD11BDAu;
  x0 += k0; x1 += k1;
#define RR(r) { x0 += x1; x1 = (x1 << (r)) | (x1 >> (32 - (r))); x1 ^= x0; }
  RR(13) RR(15) RR(26) RR(6)
  x0 += k1; x1 += k2 + 1u;
  RR(17) RR(29) RR(16) RR(24)
  x0 += k2; x1 += k0 + 2u;
  RR(13) RR(15) RR(26) RR(6)
  x0 += k0; x1 += k1 + 3u;
  RR(17) RR(29) RR(16) RR(24)
  x0 += k1; x1 += k2 + 4u;
  RR(13) RR(15) RR(26) RR(6)
  x0 += k2; x1 += k0 + 5u;
#undef RR
  U2 r; r.a = x0; r.b = x1; return r;
}

// fast tanh for attention scores (numerics preserved from passing kernels)
__device__ __forceinline__ float fast_tanh(float x) {
  float xc = fminf(fmaxf(x, -9.0f), 9.0f);
  float e = __expf(2.0f * xc);
  return (e - 1.0f) / (e + 1.0f);
}

// -------- prep: transpose + float4-pack weights into workspace --------
// WTP  : [64][512][4]  combined gate weights; kb<32 -> W_ih k=kb*4+j ; kb>=32 -> W_hh
// WoT4 : [32][128][4]  W_out^T packed
// WrT4 : [32][128][4]  W_ref^T packed
__global__ void prep_kernel(const float* __restrict__ W_ih, const float* __restrict__ W_hh,
                            const float* __restrict__ W_out, const float* __restrict__ W_ref,
                            float* __restrict__ WTP, float* __restrict__ WoT4,
                            float* __restrict__ WrT4) {
  int idx = blockIdx.x * blockDim.x + threadIdx.x;
  if (idx < 131072) {
    int j  = idx & 3;
    int r  = (idx >> 2) & 511;
    int kb = idx >> 11;
    int k  = kb * 4 + j;
    WTP[idx] = (k < Hdim) ? W_ih[r * Hdim + k] : W_hh[r * Hdim + (k - Hdim)];
  } else if (idx < 131072 + 16384) {
    int i2 = idx - 131072;
    int j = i2 & 3, o = (i2 >> 2) & 127, kb = i2 >> 9;
    WoT4[i2] = W_out[o * Hdim + (kb * 4 + j)];
  } else if (idx < 131072 + 32768) {
    int i3 = idx - 147456;
    int j = i3 & 3, o = (i3 >> 2) & 127, hb = i3 >> 9;
    WrT4[i3] = W_ref[o * Hdim + (hb * 4 + j)];
  }
}

// ------------------------------ main ------------------------------
// R13 champion (626 us): R8 structure + LDS gumbel table + s_loc indirection.
// unroll 4 everywhere (both unroll-8 variants measured worse: R7 spill at the
// 64-VGPR cap, R16 sched regression at the 128 cap). 56 VGPR, no spill.
// Per-step schedule (5 barriers):
//   B: gates combine + LSTM (256 thr)
//   C: dec_term (256 thr, LDS W_out)  ||  waves 8-15: ah_{t+1} kb 0..15 (regs)
//   D: scores (waves 0-7)             ||  waves 8-15: ah_{t+1} kb 16..31 -> s_ah
//   E: sample (waves 0-1, LDS gumbel table) -> s_loc
//   A: ax_{t+1} = wx . enc[bg, loc]   (waves 0-7)
__global__ __launch_bounds__(NTHR, 4) void actor_main(
    const float* __restrict__ enc, const float* __restrict__ h0,
    const float* __restrict__ c0, const float* __restrict__ b_ih,
    const float* __restrict__ b_hh, const float* __restrict__ go,
    const float* __restrict__ v, const float* __restrict__ WTP,
    const float* __restrict__ WoT4, const float* __restrict__ WrT4,
    float* __restrict__ out)
{
  __shared__ __align__(16) float s_encterm[GB][Tlen][Hdim]; // 50 KB
  __shared__ __align__(16) float s_xh[GB][2 * Hdim];        // x | h (x used only at t=0)
  __shared__ __align__(16) float s_c[GB][Hdim];
  __shared__ __align__(16) float s_ax[GB][4 * Hdim];        // x-partials
  __shared__ __align__(16) float s_ah[GB][4 * Hdim];        // h-partials
  __shared__ __align__(16) float s_dec[GB][Hdim];
  __shared__ __align__(16) float4 s_wout4[32 * 128];        // 64 KB W_out^T
  __shared__ float s_gum[Tlen][GB][Tlen];                   // 20 KB precomputed gumbel
  __shared__ float s_scores[GB][Tlen];
  __shared__ float s_mask[GB][Tlen];
  __shared__ __align__(16) float s_bih[4 * Hdim];
  __shared__ __align__(16) float s_bhh[4 * Hdim];
  __shared__ __align__(16) float s_v[Hdim];
  __shared__ float s_logp[GB];
  __shared__ int   s_loc[GB];

  const int tid = threadIdx.x;
  const int b0  = blockIdx.x * GB;

  // ---- init ----
  for (int i = tid; i < 4 * Hdim; i += NTHR) { s_bih[i] = b_ih[i]; s_bhh[i] = b_hh[i]; }
  for (int i = tid; i < Hdim; i += NTHR) s_v[i] = v[i];
  for (int i = tid; i < GB * Hdim; i += NTHR) {
    int b = i >> 7, jj = i & 127;
    s_xh[b][jj]        = go[jj];
    s_xh[b][Hdim + jj] = h0[(size_t)(b0 + b) * Hdim + jj];
    s_c[b][jj]         = c0[(size_t)(b0 + b) * Hdim + jj];
  }
  for (int i = tid; i < GB * Tlen; i += NTHR) (&s_mask[0][0])[i] = 0.0f;
  if (tid < GB) s_logp[tid] = 0.0f;
  {
    const float4* src = (const float4*)WoT4;
    for (int i = tid; i < 32 * 128; i += NTHR) s_wout4[i] = src[i];
  }
  // gumbel table: identical op chain as the per-step E computation
  for (int i = tid; i < Tlen * GB * Tlen; i += NTHR) {
    int t    = i / (GB * Tlen);
    int rem  = i - t * (GB * Tlen);
    int b    = rem / Tlen;
    int lane = rem - b * Tlen;
    int bg   = b0 + b;
    U2 sk = tf2x32(0u, 42u, 0u, (uint32_t)t);
    U2 rb = tf2x32(sk.a, sk.b, 0u, (uint32_t)(bg * Tlen + lane));
    uint32_t bits = rb.a ^ rb.b;
    float f = __uint_as_float((bits >> 9) | 0x3f800000u) - 1.0f;
    float u = fmaxf(f, TINYF);
    s_gum[t][b][lane] = -logf(-logf(u));
  }

  // ---- enc_term = einsum('bth,oh->bto', enc, W_ref), per-block slice ----
  {
    const float4* Wr4 = (const float4*)WrT4;
    for (int oidx = tid; oidx < GB * Tlen * Hdim; oidx += NTHR) {
      int b = oidx / (Tlen * Hdim);
      int rem = oidx - b * (Tlen * Hdim);
      int t = rem >> 7, o = rem & 127;
      const float4* ep4 = (const float4*)(enc + ((size_t)(b0 + b) * Tlen + t) * Hdim);
      float acc = 0.0f;
#pragma unroll 4
      for (int hb = 0; hb < 32; ++hb) {
        float4 e4 = ep4[hb];
        float4 w4 = Wr4[hb * 128 + o];
        acc = fmaf(e4.x, w4.x, acc); acc = fmaf(e4.y, w4.y, acc);
        acc = fmaf(e4.z, w4.z, acc); acc = fmaf(e4.w, w4.w, acc);
      }
      s_encterm[b][t][o] = acc;
    }
  }
  __syncthreads();

  const float4* W4 = (const float4*)WTP;

  // ---- A0: ax_0 (x=go, waves 0-7) and ah_0 (waves 8-15) — verbatim R8 ----
  {
    int r    = tid & 511;
    int part = tid >> 9;            // 0 = x-part, 1 = h-part
    int xoff = part * Hdim;
    int woff = part * 32;
    const float4* vA = (const float4*)&s_xh[0][xoff];
    const float4* vB = (const float4*)&s_xh[1][xoff];
    float a0 = 0.f, a1 = 0.f;
#pragma unroll 4
    for (int kb = 0; kb < 32; ++kb) {
      float4 w4 = W4[(kb + woff) * 512 + r];
      float4 f0 = vA[kb];
      float4 f1 = vB[kb];
      a0 = fmaf(f0.x, w4.x, a0); a0 = fmaf(f0.y, w4.y, a0);
      a0 = fmaf(f0.z, w4.z, a0); a0 = fmaf(f0.w, w4.w, a0);
      a1 = fmaf(f1.x, w4.x, a1); a1 = fmaf(f1.y, w4.y, a1);
      a1 = fmaf(f1.z, w4.z, a1); a1 = fmaf(f1.w, w4.w, a1);
    }
    if (part == 0) { s_ax[0][r] = a0; s_ax[1][r] = a1; }
    else           { s_ah[0][r] = a0; s_ah[1][r] = a1; }
  }
  __syncthreads();

  for (int t = 0; t < Tlen; ++t) {
    const bool not_last = (t < Tlen - 1);
    float ahA = 0.f, ahB = 0.f;          // ah_{t+1} accumulators (waves 8-15)
    const int r = tid & 511;

    // ---- B: gates = ((ax + bih) + ah) + bhh ; LSTM pointwise ----
    if (tid < GB * Hdim) {
      int b = tid >> 7, jj = tid & 127;
      float gi  = ((s_ax[b][jj]          + s_bih[jj])          + s_ah[b][jj])          + s_bhh[jj];
      float gf  = ((s_ax[b][Hdim + jj]   + s_bih[Hdim + jj])   + s_ah[b][Hdim + jj])   + s_bhh[Hdim + jj];
      float gg  = ((s_ax[b][2*Hdim + jj] + s_bih[2*Hdim + jj]) + s_ah[b][2*Hdim + jj]) + s_bhh[2*Hdim + jj];
      float gob = ((s_ax[b][3*Hdim + jj] + s_bih[3*Hdim + jj]) + s_ah[b][3*Hdim + jj]) + s_bhh[3*Hdim + jj];
      float i_ = 1.0f / (1.0f + expf(-gi));
      float f_ = 1.0f / (1.0f + expf(-gf));
      float g_ = tanhf(gg);
      float o_ = 1.0f / (1.0f + expf(-gob));
      float cn = f_ * s_c[b][jj] + i_ * g_;
      s_c[b][jj] = cn;
      s_xh[b][Hdim + jj] = o_ * tanhf(cn);
    }
    __syncthreads();

    // ---- C: dec_term (256 thr, LDS W_out)  ||  waves 8-15: ah kb 0..15 ----
    if (tid < GB * Hdim) {
      int b = tid >> 7, o = tid & 127;
      float acc = 0.0f;
#pragma unroll 4
      for (int kb = 0; kb < 32; ++kb) {
        float4 w4 = s_wout4[kb * 128 + o];
        float4 h4 = *(const float4*)&s_xh[b][Hdim + kb * 4];
        acc = fmaf(h4.x, w4.x, acc); acc = fmaf(h4.y, w4.y, acc);
        acc = fmaf(h4.z, w4.z, acc); acc = fmaf(h4.w, w4.w, acc);
      }
      s_dec[b][o] = acc;
    } else if (tid >= 512 && not_last) {
      const float4* vA = (const float4*)&s_xh[0][Hdim];
      const float4* vB = (const float4*)&s_xh[1][Hdim];
#pragma unroll 4
      for (int kb = 0; kb < 16; ++kb) {
        float4 w4 = W4[(kb + 32) * 512 + r];
        float4 f0 = vA[kb];
        float4 f1 = vB[kb];
        ahA = fmaf(f0.x, w4.x, ahA); ahA = fmaf(f0.y, w4.y, ahA);
        ahA = fmaf(f0.z, w4.z, ahA); ahA = fmaf(f0.w, w4.w, ahA);
        ahB = fmaf(f1.x, w4.x, ahB); ahB = fmaf(f1.y, w4.y, ahB);
        ahB = fmaf(f1.z, w4.z, ahB); ahB = fmaf(f1.w, w4.w, ahB);
      }
    }
    __syncthreads();

    // ---- D: scores (waves 0-7)  ||  waves 8-15: ah kb 16..31 -> s_ah ----
    if (tid < 512) {
      int w = tid >> 6, lane = tid & 63;
      float vlo = s_v[lane], vhi = s_v[lane + 64];
      for (int task = w; task < GB * Tlen; task += 8) {
        int b = task / Tlen, tt = task - b * Tlen;
        float p0 = s_encterm[b][tt][lane]      + s_dec[b][lane];
        float p1 = s_encterm[b][tt][lane + 64] + s_dec[b][lane + 64];
        float val = vlo * fast_tanh(p0) + vhi * fast_tanh(p1);
        for (int off = 32; off; off >>= 1) val += __shfl_down(val, off);
        if (lane == 0) s_scores[b][tt] = val;
      }
    } else if (not_last) {
      const float4* vA = (const float4*)&s_xh[0][Hdim];
      const float4* vB = (const float4*)&s_xh[1][Hdim];
#pragma unroll 4
      for (int kb = 16; kb < 32; ++kb) {
        float4 w4 = W4[(kb + 32) * 512 + r];
        float4 f0 = vA[kb];
        float4 f1 = vB[kb];
        ahA = fmaf(f0.x, w4.x, ahA); ahA = fmaf(f0.y, w4.y, ahA);
        ahA = fmaf(f0.z, w4.z, ahA); ahA = fmaf(f0.w, w4.w, ahA);
        ahB = fmaf(f1.x, w4.x, ahB); ahB = fmaf(f1.y, w4.y, ahB);
        ahB = fmaf(f1.z, w4.z, ahB); ahB = fmaf(f1.w, w4.w, ahB);
      }
      s_ah[0][r] = ahA; s_ah[1][r] = ahB;
    }
    __syncthreads();

    // ---- E: sample (waves 0-1, LDS gumbel) -> tour, logp, mask, s_loc ----
    {
      int w = tid >> 6;
      if (w < GB) {
        int b = w, lane = tid & 63;
        int bg = b0 + b;
        float masked_v = -3.0e38f, val = -3.0e38f;
        if (lane < Tlen) {
          float sc = s_scores[b][lane];
          float mk = s_mask[b][lane];
          masked_v = sc - BIG * mk;
          val = masked_v + s_gum[t][b][lane];
        }
        // argmax, first-index tie-break
        float bv = val; int bi = (tid & 63);
        for (int off = 32; off; off >>= 1) {
          float ov = __shfl_down(bv, off);
          int   oi = __shfl_down(bi, off);
          if (ov > bv || (ov == bv && oi < bi)) { bv = ov; bi = oi; }
        }
        bi = __shfl(bi, 0);
        // log_softmax at bi
        float mx = masked_v;
        for (int off = 32; off; off >>= 1) mx = fmaxf(mx, __shfl_down(mx, off));
        mx = __shfl(mx, 0);
        float ex = (lane < Tlen) ? expf(masked_v - mx) : 0.0f;
        for (int off = 32; off; off >>= 1) ex += __shfl_down(ex, off);
        ex = __shfl(ex, 0);
        float msel = __shfl(masked_v, bi);
        float logp = (msel - mx) - logf(ex);
        if (lane == 0) {
          s_logp[b] += logp;
          s_mask[b][bi] += 1.0f;
          s_loc[b] = bi;
          out[Bsz + (size_t)bg * (Tlen + 1) + t] = (float)bi;
          if (t == 0) out[Bsz + (size_t)bg * (Tlen + 1) + Tlen] = (float)bi;
        }
      }
    }
    __syncthreads();

    // ---- A: ax_{t+1} = wx . enc[bg, loc]  (waves 0-7, direct L2 row reads) ----
    if (tid < 512 && not_last) {
      const float4* eA = (const float4*)(enc + ((size_t)(b0 + 0) * Tlen + s_loc[0]) * Hdim);
      const float4* eB = (const float4*)(enc + ((size_t)(b0 + 1) * Tlen + s_loc[1]) * Hdim);
      float a0 = 0.f, a1 = 0.f;
#pragma unroll 4
      for (int kb = 0; kb < 32; ++kb) {
        float4 w4 = W4[kb * 512 + r];
        float4 f0 = eA[kb];
        float4 f1 = eB[kb];
        a0 = fmaf(f0.x, w4.x, a0); a0 = fmaf(f0.y, w4.y, a0);
        a0 = fmaf(f0.z, w4.z, a0); a0 = fmaf(f0.w, w4.w, a0);
        a1 = fmaf(f1.x, w4.x, a1); a1 = fmaf(f1.y, w4.y, a1);
        a1 = fmaf(f1.z, w4.z, a1); a1 = fmaf(f1.w, w4.w, a1);
      }
      s_ax[0][r] = a0; s_ax[1][r] = a1;
    }
    __syncthreads();
  }

  if (tid < GB) out[b0 + tid] = s_logp[tid];
}

extern "C" void kernel_launch(void* const* d_in, const int* in_sizes, int n_in,
                              void* d_out, int out_size, void* d_ws, size_t ws_size,
                              hipStream_t stream) {
  const float* enc   = (const float*)d_in[0];
  const float* h0    = (const float*)d_in[1];
  const float* c0    = (const float*)d_in[2];
  const float* W_ih  = (const float*)d_in[3];
  const float* W_hh  = (const float*)d_in[4];
  const float* b_ih  = (const float*)d_in[5];
  const float* b_hh  = (const float*)d_in[6];
  const float* go    = (const float*)d_in[7];
  const float* W_ref = (const float*)d_in[8];
  const float* W_out = (const float*)d_in[9];
  const float* v     = (const float*)d_in[10];
  float* out = (float*)d_out;

  float* WTP  = (float*)d_ws;        // 131072 floats (512 KB)
  float* WoT4 = WTP + 131072;        // 16384 floats
  float* WrT4 = WoT4 + 16384;        // 16384 floats  (total 640 KB of ws)

  prep_kernel<<<640, 256, 0, stream>>>(W_ih, W_hh, W_out, W_ref, WTP, WoT4, WrT4);
  actor_main<<<NBLK, NTHR, 0, stream>>>(enc, h0, c0, b_ih, b_hh, go, v,
                                        WTP, WoT4, WrT4, out);
}